// Round 5
// baseline (2223.165 us; speedup 1.0000x reference)
//
#include <hip/hip_runtime.h>
#include <float.h>
#include <math.h>

#define B_ 8
#define N_ 1024
#define C_ 768
#define H_ 12
#define HD_ 64
#define BH_ (B_*H_)

// ordered-uint pack: bigger key = (bigger value) or (equal value, smaller idx)
__device__ __forceinline__ unsigned long long makekey(float v, int idx) {
    unsigned int b = __float_as_uint(v);
    unsigned int o = (b & 0x80000000u) ? ~b : (b | 0x80000000u);
    return ((unsigned long long)o << 32) | (unsigned int)(1023 - idx);
}

__device__ __forceinline__ unsigned long long shflxor64(unsigned long long x, int m) {
    unsigned int lo = (unsigned int)x, hi = (unsigned int)(x >> 32);
    lo = __shfl_xor(lo, m);
    hi = __shfl_xor(hi, m);
    return ((unsigned long long)hi << 32) | lo;
}

// ---------------- fp32 GEMM: C[M,NN] = A[M,KD] * W[NN,KD]^T + bias ----------------
// Sequential in-order K accumulation (k=0..KD-1) with one FMA chain per element,
// bias added after — mirrors np/OpenBLAS sgemm + broadcast add.
// MODE 0: plain row-major store. MODE 1: scatter into Q/K/V [3][BH][N][64].
template<int MM, int NN, int KD, int MODE>
__global__ void __launch_bounds__(256)
gemm_k(const float* __restrict__ A, const float* __restrict__ W,
       const float* __restrict__ bias, float* __restrict__ out)
{
    __shared__ float As[16][132];
    __shared__ float Bs[16][132];
    const int tid = threadIdx.x;
    constexpr int NBLK = NN / 128;
    const int bm = blockIdx.x / NBLK;
    const int bn = blockIdx.x % NBLK;
    const int m0 = bm * 128, n0 = bn * 128;
    const int ty = tid >> 4, tx = tid & 15;
    const int ar = tid >> 2;           // 0..63
    const int ac = (tid & 3) << 2;     // 0,4,8,12

    float acc[8][8];
#pragma unroll
    for (int i = 0; i < 8; ++i)
#pragma unroll
        for (int j = 0; j < 8; ++j) acc[i][j] = 0.f;

    const float* A0 = A + (size_t)(m0 + ar) * KD + ac;
    const float* A1 = A + (size_t)(m0 + ar + 64) * KD + ac;
    const float* W0 = W + (size_t)(n0 + ar) * KD + ac;
    const float* W1 = W + (size_t)(n0 + ar + 64) * KD + ac;

    float4 pa0 = *(const float4*)A0;
    float4 pa1 = *(const float4*)A1;
    float4 pb0 = *(const float4*)W0;
    float4 pb1 = *(const float4*)W1;

    for (int k0 = 0; k0 < KD; k0 += 16) {
        __syncthreads();
        As[ac+0][ar]    = pa0.x; As[ac+1][ar]    = pa0.y; As[ac+2][ar]    = pa0.z; As[ac+3][ar]    = pa0.w;
        As[ac+0][ar+64] = pa1.x; As[ac+1][ar+64] = pa1.y; As[ac+2][ar+64] = pa1.z; As[ac+3][ar+64] = pa1.w;
        Bs[ac+0][ar]    = pb0.x; Bs[ac+1][ar]    = pb0.y; Bs[ac+2][ar]    = pb0.z; Bs[ac+3][ar]    = pb0.w;
        Bs[ac+0][ar+64] = pb1.x; Bs[ac+1][ar+64] = pb1.y; Bs[ac+2][ar+64] = pb1.z; Bs[ac+3][ar+64] = pb1.w;
        __syncthreads();
        if (k0 + 16 < KD) {
            pa0 = *(const float4*)(A0 + k0 + 16);
            pa1 = *(const float4*)(A1 + k0 + 16);
            pb0 = *(const float4*)(W0 + k0 + 16);
            pb1 = *(const float4*)(W1 + k0 + 16);
        }
#pragma unroll
        for (int kk = 0; kk < 16; ++kk) {
            float4 a0v = *(const float4*)&As[kk][ty * 4];
            float4 a1v = *(const float4*)&As[kk][64 + ty * 4];
            float4 b0v = *(const float4*)&Bs[kk][tx * 4];
            float4 b1v = *(const float4*)&Bs[kk][64 + tx * 4];
            float av[8] = {a0v.x,a0v.y,a0v.z,a0v.w, a1v.x,a1v.y,a1v.z,a1v.w};
            float bv[8] = {b0v.x,b0v.y,b0v.z,b0v.w, b1v.x,b1v.y,b1v.z,b1v.w};
#pragma unroll
            for (int i = 0; i < 8; ++i)
#pragma unroll
                for (int j = 0; j < 8; ++j)
                    acc[i][j] = fmaf(av[i], bv[j], acc[i][j]);
        }
    }

#pragma unroll
    for (int gi = 0; gi < 2; ++gi)
#pragma unroll
    for (int i = 0; i < 4; ++i) {
        const int m = m0 + gi * 64 + ty * 4 + i;
        const int ai = gi * 4 + i;
#pragma unroll
        for (int gj = 0; gj < 2; ++gj) {
            const int o = n0 + gj * 64 + tx * 4;
            const int aj = gj * 4;
            float4 bv4 = *(const float4*)(bias + o);
            float4 v;
            v.x = acc[ai][aj+0] + bv4.x;
            v.y = acc[ai][aj+1] + bv4.y;
            v.z = acc[ai][aj+2] + bv4.z;
            v.w = acc[ai][aj+3] + bv4.w;
            if (MODE == 0) {
                *(float4*)(out + (size_t)m * NN + o) = v;
            } else {
                const int which = o / 768;           // 0=Q,1=K,2=V
                const int r = o - which * 768;
                const int hh = r >> 6;
                const int dd = r & 63;
                float* dst = out + (size_t)which * ((size_t)BH_ * N_ * HD_)
                           + ((size_t)((m >> 10) * H_ + hh) * N_ + (m & 1023)) * HD_ + dd;
                *(float4*)dst = v;
            }
        }
    }
}

// ---------------- fused scores + top-16 + renorm + PV (all fp32, np-order) ----------------
// grid: BH_*64 blocks, 256 threads (4 waves). Each block: 16 q-rows.
// Wave w owns j in [w*256, w*256+256); thread tile = 16 rows x 4 cols (acc in regs).
__global__ void __launch_bounds__(256)
attn_k(const float* __restrict__ Qg, const float* __restrict__ Kg,
       const float* __restrict__ Vg, float* __restrict__ topk,
       float* __restrict__ aout)
{
    __shared__ float Qs[64][16];                    // [d][q]
    __shared__ float Kt[8][1032];                   // [dd][j] d-chunk of 8
    __shared__ float qm[8][64];                     // quad maxes per row
    __shared__ unsigned long long kbuf[8][384];     // survivor keys (96 per wave)
    __shared__ int cnt[8][4];

    const int tid = threadIdx.x;
    const int lane = tid & 63;
    const int w = tid >> 6;
    const int bh = blockIdx.x >> 6;
    const int qt = blockIdx.x & 63;
    const int q0 = qt << 4;
    const int b = bh / H_;
    const int h = bh - b * H_;
    const size_t kvbase = (size_t)bh * (N_ * HD_);

    {   // stage Q transposed: Qs[d][q]
        int q = tid >> 4;
        int d4 = (tid & 15) << 2;
        float4 v = *(const float4*)(Qg + kvbase + (size_t)(q0 + q) * HD_ + d4);
        Qs[d4+0][q] = v.x; Qs[d4+1][q] = v.y; Qs[d4+2][q] = v.z; Qs[d4+3][q] = v.w;
    }

    float acc[16][4];
#pragma unroll
    for (int r = 0; r < 16; ++r)
#pragma unroll
        for (int u = 0; u < 4; ++u) acc[r][u] = 0.f;

    const int jb = (w << 8) + (lane << 2);

    float4 kreg[8];
#pragma unroll
    for (int it = 0; it < 8; ++it) {
        int u = tid + (it << 8);
        int j = u >> 1, half = (u & 1) << 2;
        kreg[it] = *(const float4*)(Kg + kvbase + (size_t)j * HD_ + half);
    }

    // sequential d = 0..63 in-order fp32 FMA accumulation (np-matching)
    for (int d0 = 0; d0 < 64; d0 += 8) {
        __syncthreads();
#pragma unroll
        for (int it = 0; it < 8; ++it) {
            int u = tid + (it << 8);
            int j = u >> 1, half = (u & 1) << 2;
            Kt[half+0][j] = kreg[it].x; Kt[half+1][j] = kreg[it].y;
            Kt[half+2][j] = kreg[it].z; Kt[half+3][j] = kreg[it].w;
        }
        __syncthreads();
        if (d0 + 8 < 64) {
#pragma unroll
            for (int it = 0; it < 8; ++it) {
                int u = tid + (it << 8);
                int j = u >> 1, half = (u & 1) << 2;
                kreg[it] = *(const float4*)(Kg + kvbase + (size_t)j * HD_ + (d0 + 8) + half);
            }
        }
#pragma unroll
        for (int dd = 0; dd < 8; ++dd) {
            const float* qrow = &Qs[d0 + dd][0];
            float4 q0v = *(const float4*)(qrow + 0);
            float4 q1v = *(const float4*)(qrow + 4);
            float4 q2v = *(const float4*)(qrow + 8);
            float4 q3v = *(const float4*)(qrow + 12);
            float4 kb = *(const float4*)&Kt[dd][jb];
            float qv[16] = {q0v.x,q0v.y,q0v.z,q0v.w, q1v.x,q1v.y,q1v.z,q1v.w,
                            q2v.x,q2v.y,q2v.z,q2v.w, q3v.x,q3v.y,q3v.z,q3v.w};
            float bv[4] = {kb.x, kb.y, kb.z, kb.w};
#pragma unroll
            for (int r = 0; r < 16; ++r)
#pragma unroll
                for (int u = 0; u < 4; ++u)
                    acc[r][u] = fmaf(qv[r], bv[u], acc[r][u]);
        }
    }

    // scale (exact pow2 -> ordering-safe)
#pragma unroll
    for (int r = 0; r < 16; ++r)
#pragma unroll
        for (int u = 0; u < 4; ++u) acc[r][u] *= 0.125f;

#pragma unroll 1
    for (int pass = 0; pass < 2; ++pass) {
        // (a) per-row quad maxes (16 values per quad of lanes)
#pragma unroll
        for (int rr = 0; rr < 8; ++rr) {
            const int r = pass * 8 + rr;
            float lm = fmaxf(fmaxf(acc[r][0], acc[r][1]), fmaxf(acc[r][2], acc[r][3]));
            lm = fmaxf(lm, __shfl_xor(lm, 1));
            lm = fmaxf(lm, __shfl_xor(lm, 2));
            if ((lane & 3) == 0) qm[rr][(w << 4) + (lane >> 2)] = lm;
        }
        __syncthreads();
        // (c) threshold T = min of 16 disjoint supergroup-maxes (<= s(16)); compact survivors
#pragma unroll
        for (int rr = 0; rr < 8; ++rr) {
            const int r = pass * 8 + rr;
            const int g = lane & 15;
            float sg = fmaxf(fmaxf(qm[rr][g], qm[rr][16 + g]),
                             fmaxf(qm[rr][32 + g], qm[rr][48 + g]));
            sg = fminf(sg, __shfl_xor(sg, 1));
            sg = fminf(sg, __shfl_xor(sg, 2));
            sg = fminf(sg, __shfl_xor(sg, 4));
            sg = fminf(sg, __shfl_xor(sg, 8));
            const float T = sg;
            int base = 0;
            unsigned long long lowmask = (lane == 0) ? 0ull : ((1ull << lane) - 1ull);
#pragma unroll
            for (int u = 0; u < 4; ++u) {
                bool f = acc[r][u] >= T;
                unsigned long long m = __ballot(f);
                int pos = base + __popcll(m & lowmask);
                if (f && pos < 96) kbuf[rr][w * 96 + pos] = makekey(acc[r][u], jb + u);
                base += __popcll(m);
            }
            if (lane == 0) cnt[rr][w] = base < 96 ? base : 96;
        }
        __syncthreads();
        // (e) per-wave: 2 rows; packed 6-slot pool tournament, then epilogue
#pragma unroll 1
        for (int rr2 = 0; rr2 < 2; ++rr2) {
            const int rr = (w << 1) + rr2;
            const int rglob = pass * 8 + rr;
            const int c0n = cnt[rr][0], c1n = cnt[rr][1], c2n = cnt[rr][2], c3n = cnt[rr][3];
            const int pfx1 = c0n, pfx2 = c0n + c1n, pfx3 = c0n + c1n + c2n;
            const int Ctot = pfx3 + c3n;             // 16..384

            // map packed position p -> key (0 if invalid)
            auto mapk = [&](int p) -> unsigned long long {
                if (p >= Ctot) return 0ull;
                int wseg, pos;
                if (p < pfx1)      { wseg = 0; pos = p; }
                else if (p < pfx2) { wseg = 1; pos = p - pfx1; }
                else if (p < pfx3) { wseg = 2; pos = p - pfx2; }
                else               { wseg = 3; pos = p - pfx3; }
                return kbuf[rr][wseg * 96 + pos];
            };

            unsigned long long kk0 = mapk(lane);
            unsigned long long kk1 = mapk(lane + 64);
            unsigned long long kk2 = mapk(lane + 128);
            unsigned long long kk3 = mapk(lane + 192);
            unsigned long long kk4 = mapk(lane + 256);
            unsigned long long kk5 = mapk(lane + 320);

            unsigned long long resk = 0ull;
#pragma unroll 1
            for (int round = 0; round < 16; ++round) {
                unsigned long long hk = kk0;
                if (kk1 > hk) hk = kk1;
                if (kk2 > hk) hk = kk2;
                if (kk3 > hk) hk = kk3;
                if (kk4 > hk) hk = kk4;
                if (kk5 > hk) hk = kk5;
                unsigned long long bk = hk;
#pragma unroll
                for (int off = 1; off < 64; off <<= 1) {
                    unsigned long long o = shflxor64(bk, off);
                    if (o > bk) bk = o;
                }
                if (hk == bk && bk != 0ull) {       // unique owner (keys distinct)
                    if (kk0 == bk) kk0 = 0ull;
                    else if (kk1 == bk) kk1 = 0ull;
                    else if (kk2 == bk) kk2 = 0ull;
                    else if (kk3 == bk) kk3 = 0ull;
                    else if (kk4 == bk) kk4 = 0ull;
                    else kk5 = 0ull;
                }
                if (lane == round) resk = bk;
            }

            // lanes 0..15 hold rank-l (value, index)
            unsigned int ordv = (unsigned int)(resk >> 32);
            unsigned int fb = (ordv & 0x80000000u) ? (ordv & 0x7FFFFFFFu) : ~ordv;
            float rv = __uint_as_float(fb);
            int ridx = 1023 - (int)(resk & 0xFFFFFFFFull);

            float mx = __shfl(rv, 0);
            float e = expf(rv - mx);
            float ssum = e;
            ssum += __shfl_xor(ssum, 1);
            ssum += __shfl_xor(ssum, 2);
            ssum += __shfl_xor(ssum, 4);
            ssum += __shfl_xor(ssum, 8);
            float wgt = e / ssum;

            float rwv[16]; int rjj[16];
#pragma unroll
            for (int t = 0; t < 16; ++t) { rwv[t] = __shfl(wgt, t); rjj[t] = __shfl(ridx, t); }

            const size_t rowbase = ((size_t)bh * N_ + (q0 + rglob)) * N_;
            float4 z4; z4.x = z4.y = z4.z = z4.w = 0.f;
#pragma unroll
            for (int t = 0; t < 4; ++t)
                *(float4*)(topk + rowbase + (size_t)(((t << 6) + lane) << 2)) = z4;

            float pacc = 0.f;
#pragma unroll
            for (int t = 0; t < 16; ++t)
                pacc = fmaf(rwv[t], Vg[kvbase + ((size_t)rjj[t] << 6) + lane], pacc);

            asm volatile("s_waitcnt vmcnt(0)" ::: "memory");   // order zero-fill before scatter
            if (lane < 16) topk[rowbase + ridx] = wgt;
            aout[((size_t)(b * N_ + q0 + rglob)) * C_ + (h << 6) + lane] = pacc;
        }
        __syncthreads();
    }
}

extern "C" void kernel_launch(void* const* d_in, const int* in_sizes, int n_in,
                              void* d_out, int out_size, void* d_ws, size_t ws_size,
                              hipStream_t stream)
{
    (void)in_sizes; (void)n_in; (void)out_size; (void)ws_size;
    const float* query = (const float*)d_in[0];
    const float* win   = (const float*)d_in[1];
    const float* bin   = (const float*)d_in[2];
    const float* wout  = (const float*)d_in[3];
    const float* bout  = (const float*)d_in[4];

    float* ws = (float*)d_ws;
    float* Qp = ws;
    float* Kp = Qp + (size_t)BH_ * N_ * HD_;
    float* Vp = Kp + (size_t)BH_ * N_ * HD_;
    float* aout = Vp + (size_t)BH_ * N_ * HD_;   // [8192][768]

    float* outp = (float*)d_out;
    float* topk = outp + (size_t)B_ * N_ * C_;

    gemm_k<8192, 2304, 768, 1><<<64 * 18, 256, 0, stream>>>(query, win, bin, Qp);
    attn_k<<<BH_ * 64, 256, 0, stream>>>(Qp, Kp, Vp, topk, aout);
    gemm_k<8192, 768, 768, 0><<<64 * 6, 256, 0, stream>>>(aout, wout, bout, outp);
}

// Round 7
// 1127.826 us; speedup vs baseline: 1.9712x; 1.9712x over previous
//
#include <hip/hip_runtime.h>
#include <float.h>
#include <math.h>

#define B_ 8
#define N_ 1024
#define C_ 768
#define H_ 12
#define HD_ 64
#define BH_ (B_*H_)

// ordered-uint pack: bigger key = (bigger value) or (equal value, smaller idx)
__device__ __forceinline__ unsigned long long makekey(float v, int idx) {
    unsigned int b = __float_as_uint(v);
    unsigned int o = (b & 0x80000000u) ? ~b : (b | 0x80000000u);
    return ((unsigned long long)o << 32) | (unsigned int)(1023 - idx);
}
__device__ __forceinline__ float keyval(unsigned long long k) {
    unsigned int ordv = (unsigned int)(k >> 32);
    unsigned int fb = (ordv & 0x80000000u) ? (ordv & 0x7FFFFFFFu) : ~ordv;
    return __uint_as_float(fb);
}

// ---------------- fp32 GEMM: C[M,NN] = A[M,KD] * W[NN,KD]^T + bias ----------------
// Sequential in-order K accumulation; bias added after (np-matching).
// MODE 0: plain row-major store. MODE 1: scatter Q row-major / K TRANSPOSED / V row-major.
template<int MM, int NN, int KD, int MODE>
__global__ void __launch_bounds__(256)
gemm_k(const float* __restrict__ A, const float* __restrict__ W,
       const float* __restrict__ bias, float* __restrict__ out)
{
    __shared__ float As[16][132];
    __shared__ float Bs[16][132];
    const int tid = threadIdx.x;
    constexpr int NBLK = NN / 128;
    const int bm = blockIdx.x / NBLK;
    const int bn = blockIdx.x % NBLK;
    const int m0 = bm * 128, n0 = bn * 128;
    const int ty = tid >> 4, tx = tid & 15;
    const int ar = tid >> 2;           // 0..63
    const int ac = (tid & 3) << 2;     // 0,4,8,12

    float acc[8][8];
#pragma unroll
    for (int i = 0; i < 8; ++i)
#pragma unroll
        for (int j = 0; j < 8; ++j) acc[i][j] = 0.f;

    const float* A0 = A + (size_t)(m0 + ar) * KD + ac;
    const float* A1 = A + (size_t)(m0 + ar + 64) * KD + ac;
    const float* W0 = W + (size_t)(n0 + ar) * KD + ac;
    const float* W1 = W + (size_t)(n0 + ar + 64) * KD + ac;

    float4 pa0 = *(const float4*)A0;
    float4 pa1 = *(const float4*)A1;
    float4 pb0 = *(const float4*)W0;
    float4 pb1 = *(const float4*)W1;

    for (int k0 = 0; k0 < KD; k0 += 16) {
        __syncthreads();
        As[ac+0][ar]    = pa0.x; As[ac+1][ar]    = pa0.y; As[ac+2][ar]    = pa0.z; As[ac+3][ar]    = pa0.w;
        As[ac+0][ar+64] = pa1.x; As[ac+1][ar+64] = pa1.y; As[ac+2][ar+64] = pa1.z; As[ac+3][ar+64] = pa1.w;
        Bs[ac+0][ar]    = pb0.x; Bs[ac+1][ar]    = pb0.y; Bs[ac+2][ar]    = pb0.z; Bs[ac+3][ar]    = pb0.w;
        Bs[ac+0][ar+64] = pb1.x; Bs[ac+1][ar+64] = pb1.y; Bs[ac+2][ar+64] = pb1.z; Bs[ac+3][ar+64] = pb1.w;
        __syncthreads();
        if (k0 + 16 < KD) {
            pa0 = *(const float4*)(A0 + k0 + 16);
            pa1 = *(const float4*)(A1 + k0 + 16);
            pb0 = *(const float4*)(W0 + k0 + 16);
            pb1 = *(const float4*)(W1 + k0 + 16);
        }
#pragma unroll
        for (int kk = 0; kk < 16; ++kk) {
            float4 a0v = *(const float4*)&As[kk][ty * 4];
            float4 a1v = *(const float4*)&As[kk][64 + ty * 4];
            float4 b0v = *(const float4*)&Bs[kk][tx * 4];
            float4 b1v = *(const float4*)&Bs[kk][64 + tx * 4];
            float av[8] = {a0v.x,a0v.y,a0v.z,a0v.w, a1v.x,a1v.y,a1v.z,a1v.w};
            float bv[8] = {b0v.x,b0v.y,b0v.z,b0v.w, b1v.x,b1v.y,b1v.z,b1v.w};
#pragma unroll
            for (int i = 0; i < 8; ++i)
#pragma unroll
                for (int j = 0; j < 8; ++j)
                    acc[i][j] = fmaf(av[i], bv[j], acc[i][j]);
        }
    }

#pragma unroll
    for (int gi = 0; gi < 2; ++gi)
#pragma unroll
    for (int i = 0; i < 4; ++i) {
        const int m = m0 + gi * 64 + ty * 4 + i;
        const int ai = gi * 4 + i;
#pragma unroll
        for (int gj = 0; gj < 2; ++gj) {
            const int o = n0 + gj * 64 + tx * 4;
            const int aj = gj * 4;
            float4 bv4 = *(const float4*)(bias + o);
            float4 v;
            v.x = acc[ai][aj+0] + bv4.x;
            v.y = acc[ai][aj+1] + bv4.y;
            v.z = acc[ai][aj+2] + bv4.z;
            v.w = acc[ai][aj+3] + bv4.w;
            if (MODE == 0) {
                *(float4*)(out + (size_t)m * NN + o) = v;
            } else {
                const int which = o / 768;           // 0=Q,1=K,2=V
                const int r = o - which * 768;
                const int hh = r >> 6;
                const int dd = r & 63;
                const int bh = (m >> 10) * H_ + hh;
                const int nn = m & 1023;
                if (which == 1) {
                    // K TRANSPOSED: [bh][d][n]
                    float* dst = out + (size_t)BH_ * N_ * HD_
                               + ((size_t)bh * HD_ + dd) * N_ + nn;
                    dst[0]      = v.x;
                    dst[N_]     = v.y;
                    dst[2 * N_] = v.z;
                    dst[3 * N_] = v.w;
                } else {
                    float* dst = out + (size_t)which * ((size_t)BH_ * N_ * HD_)
                               + ((size_t)bh * N_ + nn) * HD_ + dd;
                    *(float4*)dst = v;
                }
            }
        }
    }
}

// ------- fused scores + top-16 (rank-count) + renorm + PV; compact winner list -------
// grid: BH_*64 = 6144 blocks (XCD-swizzled), 256 threads (4 waves). Each block: 16 q-rows.
__global__ void __launch_bounds__(256)
attn_k(const float* __restrict__ Qg, const float* __restrict__ Ktg,
       const float* __restrict__ Vg, uint2* __restrict__ wlist,
       float* __restrict__ aout)
{
    __shared__ float Qs[64][16];                    // [d][q]
    __shared__ float qm[8][64];                     // quad maxes per row
    __shared__ unsigned long long kbuf[8][384];     // survivor keys (96 per wave)
    __shared__ int cnt[8][4];
    __shared__ uint2 w16s[8][16];                   // winners by rank (idx, wgt-bits)

    const int tid = threadIdx.x;
    const int lane = tid & 63;
    const int w = tid >> 6;
    // XCD-aware BIJECTIVE swizzle: 6144 blocks = 8 XCDs x 768 chunks (6144%8==0)
    const int eff = (blockIdx.x & 7) * 768 + (blockIdx.x >> 3);
    const int bh = eff >> 6;
    const int qt = eff & 63;
    const int q0 = qt << 4;
    const int b = bh / H_;
    const int h = bh - b * H_;
    const size_t kvbase = (size_t)bh * (N_ * HD_);

    {   // stage Q transposed: Qs[d][q]
        int q = tid >> 4;
        int d4 = (tid & 15) << 2;
        float4 v = *(const float4*)(Qg + kvbase + (size_t)(q0 + q) * HD_ + d4);
        Qs[d4+0][q] = v.x; Qs[d4+1][q] = v.y; Qs[d4+2][q] = v.z; Qs[d4+3][q] = v.w;
    }
    __syncthreads();

    float acc[16][4];
#pragma unroll
    for (int r = 0; r < 16; ++r)
#pragma unroll
        for (int u = 0; u < 4; ++u) acc[r][u] = 0.f;

    const int jb = (w << 8) + (lane << 2);
    const float* kcol = Ktg + kvbase + jb;          // K^T [d][j], + d*1024

    // sequential d = 0..63 in-order fp32 FMA accumulation (np-matching)
#pragma unroll 8
    for (int d = 0; d < 64; ++d) {
        float4 kv = *(const float4*)(kcol + (d << 10));
        float4 q0v = *(const float4*)&Qs[d][0];
        float4 q1v = *(const float4*)&Qs[d][4];
        float4 q2v = *(const float4*)&Qs[d][8];
        float4 q3v = *(const float4*)&Qs[d][12];
        float qv[16] = {q0v.x,q0v.y,q0v.z,q0v.w, q1v.x,q1v.y,q1v.z,q1v.w,
                        q2v.x,q2v.y,q2v.z,q2v.w, q3v.x,q3v.y,q3v.z,q3v.w};
        float bv[4] = {kv.x, kv.y, kv.z, kv.w};
#pragma unroll
        for (int r = 0; r < 16; ++r)
#pragma unroll
            for (int u = 0; u < 4; ++u)
                acc[r][u] = fmaf(qv[r], bv[u], acc[r][u]);
    }

    // scale (exact pow2 -> ordering-safe)
#pragma unroll
    for (int r = 0; r < 16; ++r)
#pragma unroll
        for (int u = 0; u < 4; ++u) acc[r][u] *= 0.125f;

#pragma unroll 1
    for (int pass = 0; pass < 2; ++pass) {
        // (a) per-row quad maxes
#pragma unroll
        for (int rr = 0; rr < 8; ++rr) {
            const int r = pass * 8 + rr;
            float lm = fmaxf(fmaxf(acc[r][0], acc[r][1]), fmaxf(acc[r][2], acc[r][3]));
            lm = fmaxf(lm, __shfl_xor(lm, 1));
            lm = fmaxf(lm, __shfl_xor(lm, 2));
            if ((lane & 3) == 0) qm[rr][(w << 4) + (lane >> 2)] = lm;
        }
        __syncthreads();
        // (c) threshold T = min of 16 disjoint supergroup-maxes; compact survivors
#pragma unroll
        for (int rr = 0; rr < 8; ++rr) {
            const int r = pass * 8 + rr;
            const int g = lane & 15;
            float sg = fmaxf(fmaxf(qm[rr][g], qm[rr][16 + g]),
                             fmaxf(qm[rr][32 + g], qm[rr][48 + g]));
            sg = fminf(sg, __shfl_xor(sg, 1));
            sg = fminf(sg, __shfl_xor(sg, 2));
            sg = fminf(sg, __shfl_xor(sg, 4));
            sg = fminf(sg, __shfl_xor(sg, 8));
            const float T = sg;
            int base = 0;
            unsigned long long lowmask = (lane == 0) ? 0ull : ((1ull << lane) - 1ull);
#pragma unroll
            for (int u = 0; u < 4; ++u) {
                bool f = acc[r][u] >= T;
                unsigned long long m = __ballot(f);
                int pos = base + __popcll(m & lowmask);
                if (f && pos < 96) kbuf[rr][w * 96 + pos] = makekey(acc[r][u], jb + u);
                base += __popcll(m);
            }
            if (lane == 0) cnt[rr][w] = base < 96 ? base : 96;
        }
        __syncthreads();
        // (e) per-wave: 2 rows; data-parallel rank-count selection + epilogue
#pragma unroll 1
        for (int rr2 = 0; rr2 < 2; ++rr2) {
            const int rr = (w << 1) + rr2;
            const int rglob = pass * 8 + rr;
            const int c0n = cnt[rr][0], c1n = cnt[rr][1], c2n = cnt[rr][2], c3n = cnt[rr][3];
            const int pfx1 = c0n, pfx2 = c0n + c1n, pfx3 = c0n + c1n + c2n;
            const int Ctot = pfx3 + c3n;             // 16..384

            // my survivors: packed positions lane + 64*slot
            auto mapk = [&](int p) -> unsigned long long {
                if (p >= Ctot) return 0ull;
                int wseg, pos;
                if (p < pfx1)      { wseg = 0; pos = p; }
                else if (p < pfx2) { wseg = 1; pos = p - pfx1; }
                else if (p < pfx3) { wseg = 2; pos = p - pfx2; }
                else               { wseg = 3; pos = p - pfx3; }
                return kbuf[rr][wseg * 96 + pos];
            };
            unsigned long long kk0 = mapk(lane);
            unsigned long long kk1 = mapk(lane + 64);
            unsigned long long kk2 = mapk(lane + 128);
            unsigned long long kk3 = mapk(lane + 192);
            unsigned long long kk4 = mapk(lane + 256);
            unsigned long long kk5 = mapk(lane + 320);

            // rank = #{keys strictly greater}; keys unique; invalid (0) -> rank >= C >= 16
            int n0 = 0, n1 = 0, n2 = 0, n3 = 0, n4 = 0, n5 = 0;
#pragma unroll 1
            for (int seg = 0; seg < 4; ++seg) {
                const int cn = cnt[rr][seg];
                const unsigned long long* sp = &kbuf[rr][seg * 96];
#pragma unroll 2
                for (int p = 0; p < cn; ++p) {
                    unsigned long long kp = sp[p];   // broadcast read
                    n0 += (kp > kk0); n1 += (kp > kk1); n2 += (kp > kk2);
                    n3 += (kp > kk3); n4 += (kp > kk4); n5 += (kp > kk5);
                }
            }

            float v0 = keyval(kk0), v1 = keyval(kk1), v2 = keyval(kk2);
            float v3 = keyval(kk3), v4 = keyval(kk4), v5 = keyval(kk5);

            // m = value of rank-0 (row max)
            float mc = -FLT_MAX;
            if (n0 == 0) mc = v0;
            if (n1 == 0) mc = v1;
            if (n2 == 0) mc = v2;
            if (n3 == 0) mc = v3;
            if (n4 == 0) mc = v4;
            if (n5 == 0) mc = v5;
#pragma unroll
            for (int off = 1; off < 64; off <<= 1) mc = fmaxf(mc, __shfl_xor(mc, off));

            float e0 = (n0 < 16) ? expf(v0 - mc) : 0.f;
            float e1 = (n1 < 16) ? expf(v1 - mc) : 0.f;
            float e2 = (n2 < 16) ? expf(v2 - mc) : 0.f;
            float e3 = (n3 < 16) ? expf(v3 - mc) : 0.f;
            float e4 = (n4 < 16) ? expf(v4 - mc) : 0.f;
            float e5 = (n5 < 16) ? expf(v5 - mc) : 0.f;
            float es = e0 + e1 + e2 + e3 + e4 + e5;
#pragma unroll
            for (int off = 1; off < 64; off <<= 1) es += __shfl_xor(es, off);

            if (n0 < 16) w16s[rr][n0] = make_uint2(1023u - (unsigned)(kk0 & 0xFFFFFFFFull), __float_as_uint(e0 / es));
            if (n1 < 16) w16s[rr][n1] = make_uint2(1023u - (unsigned)(kk1 & 0xFFFFFFFFull), __float_as_uint(e1 / es));
            if (n2 < 16) w16s[rr][n2] = make_uint2(1023u - (unsigned)(kk2 & 0xFFFFFFFFull), __float_as_uint(e2 / es));
            if (n3 < 16) w16s[rr][n3] = make_uint2(1023u - (unsigned)(kk3 & 0xFFFFFFFFull), __float_as_uint(e3 / es));
            if (n4 < 16) w16s[rr][n4] = make_uint2(1023u - (unsigned)(kk4 & 0xFFFFFFFFull), __float_as_uint(e4 / es));
            if (n5 < 16) w16s[rr][n5] = make_uint2(1023u - (unsigned)(kk5 & 0xFFFFFFFFull), __float_as_uint(e5 / es));
            asm volatile("s_waitcnt lgkmcnt(0)" ::: "memory");   // in-wave LDS write->read ordering
            __builtin_amdgcn_sched_barrier(0);

            // PV (rank order, same fp32 chain as before) + compact winner list
            float pacc = 0.f;
            const float* vb = Vg + kvbase;
#pragma unroll
            for (int t = 0; t < 16; ++t) {
                uint2 ent = w16s[rr][t];
                pacc = fmaf(__uint_as_float(ent.y), vb[((size_t)ent.x << 6) + lane], pacc);
            }
            aout[((size_t)(b * N_ + q0 + rglob)) * C_ + (h << 6) + lane] = pacc;
            if (lane < 16)
                wlist[((size_t)bh * N_ + q0 + rglob) * 16 + lane] = w16s[rr][lane];
        }
        __syncthreads();
    }
}

// ---------------- topk zero-fill + scatter (pure BW) ----------------
// grid: BH_*N_/4 blocks, 256 threads (4 waves, 1 row per wave)
__global__ void __launch_bounds__(256)
scatter_k(const uint2* __restrict__ wlist, float* __restrict__ topk)
{
    const int tid = threadIdx.x;
    const int lane = tid & 63;
    const int row = (blockIdx.x << 2) + (tid >> 6);
    const size_t base = (size_t)row << 10;
    float4 z4; z4.x = z4.y = z4.z = z4.w = 0.f;
#pragma unroll
    for (int t = 0; t < 4; ++t)
        *(float4*)(topk + base + (size_t)(((t << 6) + lane) << 2)) = z4;
    asm volatile("s_waitcnt vmcnt(0)" ::: "memory");   // zero-fill before scatter
    if (lane < 16) {
        uint2 e = wlist[(size_t)row * 16 + lane];
        topk[base + e.x] = __uint_as_float(e.y);
    }
}

extern "C" void kernel_launch(void* const* d_in, const int* in_sizes, int n_in,
                              void* d_out, int out_size, void* d_ws, size_t ws_size,
                              hipStream_t stream)
{
    (void)in_sizes; (void)n_in; (void)out_size; (void)ws_size;
    const float* query = (const float*)d_in[0];
    const float* win   = (const float*)d_in[1];
    const float* bin   = (const float*)d_in[2];
    const float* wout  = (const float*)d_in[3];
    const float* bout  = (const float*)d_in[4];

    float* ws = (float*)d_ws;
    float* Qp   = ws;                                   // [BH][N][64]
    float* Ktg  = Qp  + (size_t)BH_ * N_ * HD_;         // [BH][64][N]  (K transposed)
    float* Vp   = Ktg + (size_t)BH_ * N_ * HD_;         // [BH][N][64]
    float* aout = Vp  + (size_t)BH_ * N_ * HD_;         // [8192][768]
    uint2* wlist = (uint2*)(aout + (size_t)B_ * N_ * C_); // [BH*N][16]

    float* outp = (float*)d_out;
    float* topk = outp + (size_t)B_ * N_ * C_;

    gemm_k<8192, 2304, 768, 1><<<64 * 18, 256, 0, stream>>>(query, win, bin, Qp);
    attn_k<<<BH_ * 64, 256, 0, stream>>>(Qp, Ktg, Vp, wlist, aout);
    scatter_k<<<BH_ * N_ / 4, 256, 0, stream>>>(wlist, topk);
    gemm_k<8192, 768, 768, 0><<<64 * 6, 256, 0, stream>>>(aout, wout, bout, outp);
}

// Round 8
// 1058.505 us; speedup vs baseline: 2.1003x; 1.0655x over previous
//
#include <hip/hip_runtime.h>
#include <float.h>
#include <math.h>

#define B_ 8
#define N_ 1024
#define C_ 768
#define H_ 12
#define HD_ 64
#define BH_ (B_*H_)

// ordered-uint pack: bigger key = (bigger value) or (equal value, smaller idx)
__device__ __forceinline__ unsigned long long makekey(float v, int idx) {
    unsigned int b = __float_as_uint(v);
    unsigned int o = (b & 0x80000000u) ? ~b : (b | 0x80000000u);
    return ((unsigned long long)o << 32) | (unsigned int)(1023 - idx);
}
__device__ __forceinline__ float keyval(unsigned long long k) {
    unsigned int ordv = (unsigned int)(k >> 32);
    unsigned int fb = (ordv & 0x80000000u) ? (ordv & 0x7FFFFFFFu) : ~ordv;
    return __uint_as_float(fb);
}

// ---------------- fp32 GEMM: C[M,NN] = A[M,KD] * W[NN,KD]^T + bias ----------------
// Sequential in-order K accumulation; bias added after (np-matching).
// MODE 0: plain row-major store. MODE 1: scatter Q row-major / K TRANSPOSED / V row-major.
template<int MM, int NN, int KD, int MODE>
__global__ void __launch_bounds__(256)
gemm_k(const float* __restrict__ A, const float* __restrict__ W,
       const float* __restrict__ bias, float* __restrict__ out)
{
    __shared__ float As[16][132];
    __shared__ float Bs[16][132];
    const int tid = threadIdx.x;
    constexpr int NBLK = NN / 128;
    const int bm = blockIdx.x / NBLK;
    const int bn = blockIdx.x % NBLK;
    const int m0 = bm * 128, n0 = bn * 128;
    const int ty = tid >> 4, tx = tid & 15;
    const int ar = tid >> 2;           // 0..63
    const int ac = (tid & 3) << 2;     // 0,4,8,12

    float acc[8][8];
#pragma unroll
    for (int i = 0; i < 8; ++i)
#pragma unroll
        for (int j = 0; j < 8; ++j) acc[i][j] = 0.f;

    const float* A0 = A + (size_t)(m0 + ar) * KD + ac;
    const float* A1 = A + (size_t)(m0 + ar + 64) * KD + ac;
    const float* W0 = W + (size_t)(n0 + ar) * KD + ac;
    const float* W1 = W + (size_t)(n0 + ar + 64) * KD + ac;

    float4 pa0 = *(const float4*)A0;
    float4 pa1 = *(const float4*)A1;
    float4 pb0 = *(const float4*)W0;
    float4 pb1 = *(const float4*)W1;

    for (int k0 = 0; k0 < KD; k0 += 16) {
        __syncthreads();
        As[ac+0][ar]    = pa0.x; As[ac+1][ar]    = pa0.y; As[ac+2][ar]    = pa0.z; As[ac+3][ar]    = pa0.w;
        As[ac+0][ar+64] = pa1.x; As[ac+1][ar+64] = pa1.y; As[ac+2][ar+64] = pa1.z; As[ac+3][ar+64] = pa1.w;
        Bs[ac+0][ar]    = pb0.x; Bs[ac+1][ar]    = pb0.y; Bs[ac+2][ar]    = pb0.z; Bs[ac+3][ar]    = pb0.w;
        Bs[ac+0][ar+64] = pb1.x; Bs[ac+1][ar+64] = pb1.y; Bs[ac+2][ar+64] = pb1.z; Bs[ac+3][ar+64] = pb1.w;
        __syncthreads();
        if (k0 + 16 < KD) {
            pa0 = *(const float4*)(A0 + k0 + 16);
            pa1 = *(const float4*)(A1 + k0 + 16);
            pb0 = *(const float4*)(W0 + k0 + 16);
            pb1 = *(const float4*)(W1 + k0 + 16);
        }
#pragma unroll
        for (int kk = 0; kk < 16; ++kk) {
            float4 a0v = *(const float4*)&As[kk][ty * 4];
            float4 a1v = *(const float4*)&As[kk][64 + ty * 4];
            float4 b0v = *(const float4*)&Bs[kk][tx * 4];
            float4 b1v = *(const float4*)&Bs[kk][64 + tx * 4];
            float av[8] = {a0v.x,a0v.y,a0v.z,a0v.w, a1v.x,a1v.y,a1v.z,a1v.w};
            float bv[8] = {b0v.x,b0v.y,b0v.z,b0v.w, b1v.x,b1v.y,b1v.z,b1v.w};
#pragma unroll
            for (int i = 0; i < 8; ++i)
#pragma unroll
                for (int j = 0; j < 8; ++j)
                    acc[i][j] = fmaf(av[i], bv[j], acc[i][j]);
        }
    }

#pragma unroll
    for (int gi = 0; gi < 2; ++gi)
#pragma unroll
    for (int i = 0; i < 4; ++i) {
        const int m = m0 + gi * 64 + ty * 4 + i;
        const int ai = gi * 4 + i;
#pragma unroll
        for (int gj = 0; gj < 2; ++gj) {
            const int o = n0 + gj * 64 + tx * 4;
            const int aj = gj * 4;
            float4 bv4 = *(const float4*)(bias + o);
            float4 v;
            v.x = acc[ai][aj+0] + bv4.x;
            v.y = acc[ai][aj+1] + bv4.y;
            v.z = acc[ai][aj+2] + bv4.z;
            v.w = acc[ai][aj+3] + bv4.w;
            if (MODE == 0) {
                *(float4*)(out + (size_t)m * NN + o) = v;
            } else {
                const int which = o / 768;           // 0=Q,1=K,2=V
                const int r = o - which * 768;
                const int hh = r >> 6;
                const int dd = r & 63;
                const int bh = (m >> 10) * H_ + hh;
                const int nn = m & 1023;
                if (which == 1) {
                    // K TRANSPOSED: [bh][d][n]
                    float* dst = out + (size_t)BH_ * N_ * HD_
                               + ((size_t)bh * HD_ + dd) * N_ + nn;
                    dst[0]      = v.x;
                    dst[N_]     = v.y;
                    dst[2 * N_] = v.z;
                    dst[3 * N_] = v.w;
                } else {
                    float* dst = out + (size_t)which * ((size_t)BH_ * N_ * HD_)
                               + ((size_t)bh * N_ + nn) * HD_ + dd;
                    *(float4*)dst = v;
                }
            }
        }
    }
}

// ------- fused scores + top-16 (tiered rank-count) + renorm + PV; compact winner list -------
// grid: BH_*64 = 6144 blocks (XCD-swizzled), 256 threads (4 waves). Each block: 16 q-rows.
__global__ void __launch_bounds__(256)
attn_k(const float* __restrict__ Qg, const float* __restrict__ Ktg,
       const float* __restrict__ Vg, uint2* __restrict__ wlist,
       float* __restrict__ aout)
{
    __shared__ float Qs[64][16];                    // [d][q]
    __shared__ float qm[8][64];                     // quad maxes per row
    __shared__ unsigned long long kbuf[8][384];     // survivor keys (96 per wave)
    __shared__ int cnt[8][4];
    __shared__ uint2 w16s[8][16];                   // winners by rank (idx, wgt-bits)

    const int tid = threadIdx.x;
    const int lane = tid & 63;
    const int w = tid >> 6;
    // XCD-aware BIJECTIVE swizzle: 6144 blocks = 8 XCDs x 768 chunks (6144%8==0)
    const int eff = (blockIdx.x & 7) * 768 + (blockIdx.x >> 3);
    const int bh = eff >> 6;
    const int qt = eff & 63;
    const int q0 = qt << 4;
    const int b = bh / H_;
    const int h = bh - b * H_;
    const size_t kvbase = (size_t)bh * (N_ * HD_);

    {   // stage Q transposed: Qs[d][q]
        int q = tid >> 4;
        int d4 = (tid & 15) << 2;
        float4 v = *(const float4*)(Qg + kvbase + (size_t)(q0 + q) * HD_ + d4);
        Qs[d4+0][q] = v.x; Qs[d4+1][q] = v.y; Qs[d4+2][q] = v.z; Qs[d4+3][q] = v.w;
    }
    __syncthreads();

    float acc[16][4];
#pragma unroll
    for (int r = 0; r < 16; ++r)
#pragma unroll
        for (int u = 0; u < 4; ++u) acc[r][u] = 0.f;

    const int jb = (w << 8) + (lane << 2);
    const float* kcol = Ktg + kvbase + jb;          // K^T [d][j], + d*1024

    // sequential d = 0..63 in-order fp32 FMA accumulation (np-matching)
#pragma unroll 8
    for (int d = 0; d < 64; ++d) {
        float4 kv = *(const float4*)(kcol + (d << 10));
        float4 q0v = *(const float4*)&Qs[d][0];
        float4 q1v = *(const float4*)&Qs[d][4];
        float4 q2v = *(const float4*)&Qs[d][8];
        float4 q3v = *(const float4*)&Qs[d][12];
        float qv[16] = {q0v.x,q0v.y,q0v.z,q0v.w, q1v.x,q1v.y,q1v.z,q1v.w,
                        q2v.x,q2v.y,q2v.z,q2v.w, q3v.x,q3v.y,q3v.z,q3v.w};
        float bv[4] = {kv.x, kv.y, kv.z, kv.w};
#pragma unroll
        for (int r = 0; r < 16; ++r)
#pragma unroll
            for (int u = 0; u < 4; ++u)
                acc[r][u] = fmaf(qv[r], bv[u], acc[r][u]);
    }

    // scale (exact pow2 -> ordering-safe)
#pragma unroll
    for (int r = 0; r < 16; ++r)
#pragma unroll
        for (int u = 0; u < 4; ++u) acc[r][u] *= 0.125f;

#pragma unroll 1
    for (int pass = 0; pass < 2; ++pass) {
        // (a) per-row quad maxes
#pragma unroll
        for (int rr = 0; rr < 8; ++rr) {
            const int r = pass * 8 + rr;
            float lm = fmaxf(fmaxf(acc[r][0], acc[r][1]), fmaxf(acc[r][2], acc[r][3]));
            lm = fmaxf(lm, __shfl_xor(lm, 1));
            lm = fmaxf(lm, __shfl_xor(lm, 2));
            if ((lane & 3) == 0) qm[rr][(w << 4) + (lane >> 2)] = lm;
        }
        __syncthreads();
        // (c) threshold T = min of 16 disjoint supergroup-maxes; compact survivors
#pragma unroll
        for (int rr = 0; rr < 8; ++rr) {
            const int r = pass * 8 + rr;
            const int g = lane & 15;
            float sg = fmaxf(fmaxf(qm[rr][g], qm[rr][16 + g]),
                             fmaxf(qm[rr][32 + g], qm[rr][48 + g]));
            sg = fminf(sg, __shfl_xor(sg, 1));
            sg = fminf(sg, __shfl_xor(sg, 2));
            sg = fminf(sg, __shfl_xor(sg, 4));
            sg = fminf(sg, __shfl_xor(sg, 8));
            const float T = sg;
            int base = 0;
            unsigned long long lowmask = (lane == 0) ? 0ull : ((1ull << lane) - 1ull);
#pragma unroll
            for (int u = 0; u < 4; ++u) {
                bool f = acc[r][u] >= T;
                unsigned long long m = __ballot(f);
                int pos = base + __popcll(m & lowmask);
                if (f && pos < 96) kbuf[rr][w * 96 + pos] = makekey(acc[r][u], jb + u);
                base += __popcll(m);
            }
            if (lane == 0) cnt[rr][w] = base < 96 ? base : 96;
        }
        __syncthreads();
        // (e) per-wave: 2 rows; tiered data-parallel rank-count selection + epilogue
#pragma unroll 1
        for (int rr2 = 0; rr2 < 2; ++rr2) {
            const int rr = (w << 1) + rr2;
            const int rglob = pass * 8 + rr;
            const int c0n = cnt[rr][0], c1n = cnt[rr][1], c2n = cnt[rr][2], c3n = cnt[rr][3];
            const int pfx1 = c0n, pfx2 = c0n + c1n, pfx3 = c0n + c1n + c2n;
            const int Ctot = pfx3 + c3n;             // 16..384

            // map packed position p -> key (0 if invalid)
            auto mapk = [&](int p) -> unsigned long long {
                if (p >= Ctot) return 0ull;
                int wseg, pos;
                if (p < pfx1)      { wseg = 0; pos = p; }
                else if (p < pfx2) { wseg = 1; pos = p - pfx1; }
                else if (p < pfx3) { wseg = 2; pos = p - pfx2; }
                else               { wseg = 3; pos = p - pfx3; }
                return kbuf[rr][wseg * 96 + pos];
            };

            if (Ctot <= 128) {
                // ---- common case (~99.5%): 2 slots cover the pool ----
                unsigned long long kk0 = mapk(lane);
                unsigned long long kk1 = mapk(lane + 64);
                int n0 = 0, n1 = 0;
#pragma unroll 1
                for (int seg = 0; seg < 4; ++seg) {
                    const int cn = cnt[rr][seg];
                    const unsigned long long* sp = &kbuf[rr][seg * 96];
#pragma unroll 4
                    for (int p = 0; p < cn; ++p) {
                        unsigned long long kp = sp[p];   // broadcast read
                        n0 += (kp > kk0); n1 += (kp > kk1);
                    }
                }
                float v0 = keyval(kk0), v1 = keyval(kk1);
                float mc = -FLT_MAX;
                if (n0 == 0) mc = v0;
                if (n1 == 0) mc = v1;
#pragma unroll
                for (int off = 1; off < 64; off <<= 1) mc = fmaxf(mc, __shfl_xor(mc, off));
                float e0 = (n0 < 16) ? expf(v0 - mc) : 0.f;
                float e1 = (n1 < 16) ? expf(v1 - mc) : 0.f;
                float es = e0 + e1;
#pragma unroll
                for (int off = 1; off < 64; off <<= 1) es += __shfl_xor(es, off);
                if (n0 < 16) w16s[rr][n0] = make_uint2(1023u - (unsigned)(kk0 & 0xFFFFFFFFull), __float_as_uint(e0 / es));
                if (n1 < 16) w16s[rr][n1] = make_uint2(1023u - (unsigned)(kk1 & 0xFFFFFFFFull), __float_as_uint(e1 / es));
            } else {
                // ---- rare tail: 6 slots ----
                unsigned long long kk0 = mapk(lane);
                unsigned long long kk1 = mapk(lane + 64);
                unsigned long long kk2 = mapk(lane + 128);
                unsigned long long kk3 = mapk(lane + 192);
                unsigned long long kk4 = mapk(lane + 256);
                unsigned long long kk5 = mapk(lane + 320);
                int n0 = 0, n1 = 0, n2 = 0, n3 = 0, n4 = 0, n5 = 0;
#pragma unroll 1
                for (int seg = 0; seg < 4; ++seg) {
                    const int cn = cnt[rr][seg];
                    const unsigned long long* sp = &kbuf[rr][seg * 96];
#pragma unroll 2
                    for (int p = 0; p < cn; ++p) {
                        unsigned long long kp = sp[p];
                        n0 += (kp > kk0); n1 += (kp > kk1); n2 += (kp > kk2);
                        n3 += (kp > kk3); n4 += (kp > kk4); n5 += (kp > kk5);
                    }
                }
                float v0 = keyval(kk0), v1 = keyval(kk1), v2 = keyval(kk2);
                float v3 = keyval(kk3), v4 = keyval(kk4), v5 = keyval(kk5);
                float mc = -FLT_MAX;
                if (n0 == 0) mc = v0;
                if (n1 == 0) mc = v1;
                if (n2 == 0) mc = v2;
                if (n3 == 0) mc = v3;
                if (n4 == 0) mc = v4;
                if (n5 == 0) mc = v5;
#pragma unroll
                for (int off = 1; off < 64; off <<= 1) mc = fmaxf(mc, __shfl_xor(mc, off));
                float e0 = (n0 < 16) ? expf(v0 - mc) : 0.f;
                float e1 = (n1 < 16) ? expf(v1 - mc) : 0.f;
                float e2 = (n2 < 16) ? expf(v2 - mc) : 0.f;
                float e3 = (n3 < 16) ? expf(v3 - mc) : 0.f;
                float e4 = (n4 < 16) ? expf(v4 - mc) : 0.f;
                float e5 = (n5 < 16) ? expf(v5 - mc) : 0.f;
                float es = e0 + e1 + e2 + e3 + e4 + e5;
#pragma unroll
                for (int off = 1; off < 64; off <<= 1) es += __shfl_xor(es, off);
                if (n0 < 16) w16s[rr][n0] = make_uint2(1023u - (unsigned)(kk0 & 0xFFFFFFFFull), __float_as_uint(e0 / es));
                if (n1 < 16) w16s[rr][n1] = make_uint2(1023u - (unsigned)(kk1 & 0xFFFFFFFFull), __float_as_uint(e1 / es));
                if (n2 < 16) w16s[rr][n2] = make_uint2(1023u - (unsigned)(kk2 & 0xFFFFFFFFull), __float_as_uint(e2 / es));
                if (n3 < 16) w16s[rr][n3] = make_uint2(1023u - (unsigned)(kk3 & 0xFFFFFFFFull), __float_as_uint(e3 / es));
                if (n4 < 16) w16s[rr][n4] = make_uint2(1023u - (unsigned)(kk4 & 0xFFFFFFFFull), __float_as_uint(e4 / es));
                if (n5 < 16) w16s[rr][n5] = make_uint2(1023u - (unsigned)(kk5 & 0xFFFFFFFFull), __float_as_uint(e5 / es));
            }
            asm volatile("s_waitcnt lgkmcnt(0)" ::: "memory");   // in-wave LDS write->read ordering
            __builtin_amdgcn_sched_barrier(0);

            // PV (rank order, same fp32 chain as before) + compact winner list
            float pacc = 0.f;
            const float* vb = Vg + kvbase;
#pragma unroll
            for (int t = 0; t < 16; ++t) {
                uint2 ent = w16s[rr][t];
                pacc = fmaf(__uint_as_float(ent.y), vb[((size_t)ent.x << 6) + lane], pacc);
            }
            aout[((size_t)(b * N_ + q0 + rglob)) * C_ + (h << 6) + lane] = pacc;
            if (lane < 16)
                wlist[((size_t)bh * N_ + q0 + rglob) * 16 + lane] = w16s[rr][lane];
        }
        __syncthreads();
    }
}

// ---------------- topk zero-fill + scatter (pure BW) ----------------
// grid: BH_*N_/4 blocks, 256 threads (4 waves, 1 row per wave)
__global__ void __launch_bounds__(256)
scatter_k(const uint2* __restrict__ wlist, float* __restrict__ topk)
{
    const int tid = threadIdx.x;
    const int lane = tid & 63;
    const int row = (blockIdx.x << 2) + (tid >> 6);
    const size_t base = (size_t)row << 10;
    float4 z4; z4.x = z4.y = z4.z = z4.w = 0.f;
#pragma unroll
    for (int t = 0; t < 4; ++t)
        *(float4*)(topk + base + (size_t)(((t << 6) + lane) << 2)) = z4;
    asm volatile("s_waitcnt vmcnt(0)" ::: "memory");   // zero-fill before scatter
    if (lane < 16) {
        uint2 e = wlist[(size_t)row * 16 + lane];
        topk[base + e.x] = __uint_as_float(e.y);
    }
}

extern "C" void kernel_launch(void* const* d_in, const int* in_sizes, int n_in,
                              void* d_out, int out_size, void* d_ws, size_t ws_size,
                              hipStream_t stream)
{
    (void)in_sizes; (void)n_in; (void)out_size; (void)ws_size;
    const float* query = (const float*)d_in[0];
    const float* win   = (const float*)d_in[1];
    const float* bin   = (const float*)d_in[2];
    const float* wout  = (const float*)d_in[3];
    const float* bout  = (const float*)d_in[4];

    float* ws = (float*)d_ws;
    float* Qp   = ws;                                   // [BH][N][64]
    float* Ktg  = Qp  + (size_t)BH_ * N_ * HD_;         // [BH][64][N]  (K transposed)
    float* Vp   = Ktg + (size_t)BH_ * N_ * HD_;         // [BH][N][64]
    float* aout = Vp  + (size_t)BH_ * N_ * HD_;         // [8192][768]
    uint2* wlist = (uint2*)(aout + (size_t)B_ * N_ * C_); // [BH*N][16]

    float* outp = (float*)d_out;
    float* topk = outp + (size_t)B_ * N_ * C_;

    gemm_k<8192, 2304, 768, 1><<<64 * 18, 256, 0, stream>>>(query, win, bin, Qp);
    attn_k<<<BH_ * 64, 256, 0, stream>>>(Qp, Ktg, Vp, wlist, aout);
    scatter_k<<<BH_ * N_ / 4, 256, 0, stream>>>(wlist, topk);
    gemm_k<8192, 768, 768, 0><<<64 * 6, 256, 0, stream>>>(aout, wout, bout, outp);
}